// Round 8
// baseline (981.725 us; speedup 1.0000x reference)
//
#include <hip/hip_runtime.h>
#include <math.h>

#define NTRAIN 2000
#define DIMD 210
#define DIMI 63
#define NPERM 12
#define NCOLS 8
#define NATOM 21
#define SIGF 10.0f

// ws layout (ints):
#define WS_PERM      0        // 2520
#define WS_GTAB      6300     // 5040
#define WS_ENTOFF    11340    // 442
#define WS_ENTS      11782    // 10080
#define WS_TILEMAP   21862    // 441
// total 22303 ints (~89 KB)

// ---------------- setup: fully parallel, LDS-staged (~20us) ----------------
__global__ __launch_bounds__(512) void gdml_setup(const int* __restrict__ tril,
                                                  int* __restrict__ ws) {
  __shared__ int sPerm[NPERM * DIMD];
  __shared__ int sInv[NPERM * DIMD];
  __shared__ int sRow[DIMD], sCol[DIMD];
  __shared__ int sPairs[NATOM * 20], sNeg[NATOM * 20];
  __shared__ int sCnt[441];
  __shared__ int sScan[512];
  __shared__ int sOff[442];

  const int tid = threadIdx.x;

  for (int d = tid; d < DIMD; d += 512) {
    int a = 1;
    while ((a * (a + 1)) / 2 <= d) a++;
    sRow[d] = a;
    sCol[d] = d - (a * (a - 1)) / 2;
  }
  for (int idx = tid; idx < NPERM * DIMD; idx += 512) {
    int p = idx / DIMD, d = idx % DIMD;
    sPerm[idx] = tril[d * NPERM + p] % DIMD;
  }
  __syncthreads();
  for (int idx = tid; idx < NPERM * DIMD; idx += 512) {
    int p = idx / DIMD;
    sInv[p * DIMD + sPerm[idx]] = idx % DIMD;
  }
  if (tid < NATOM) {
    int t = tid, c = 0;
    for (int d = 0; d < DIMD; ++d) {
      if (sRow[d] == t)      { sPairs[t * 20 + c] = d; sNeg[t * 20 + c] = 0; c++; }
      else if (sCol[d] == t) { sPairs[t * 20 + c] = d; sNeg[t * 20 + c] = 1; c++; }
    }
  }
  __syncthreads();

  for (int idx = tid; idx < NPERM * DIMD; idx += 512) ws[WS_PERM + idx] = sPerm[idx];
  // gtab[(p*21+at)*20+i] = d | tw<<9 | pd<<18 | neg<<27
  //   tw = invperm[p][d]  (so diff[p][tw] = Rn[tw] - Rj[d])
  //   pd = perm[p][d]     (so diff[p][d]  = Rn[d]  - Rj[pd])
  for (int idx = tid; idx < NPERM * NATOM * 20; idx += 512) {
    int p = idx / (NATOM * 20);
    int r = idx % (NATOM * 20);
    int d = sPairs[r], neg = sNeg[r];
    int tw = sInv[p * DIMD + d];
    int pd = sPerm[p * DIMD + d];
    ws[WS_GTAB + idx] = d | (tw << 9) | (pd << 18) | (neg << 27);
  }

  // CSR counts per (A,B)
  for (int q = tid; q < 441; q += 512) {
    int A = q / NATOM, B = q % NATOM, c = 0;
    for (int i = 0; i < 20; ++i) {
      int d = sPairs[A * 20 + i];
      for (int p = 0; p < NPERM; ++p) {
        int dd = sPerm[p * DIMD + d];
        c += (sRow[dd] == B) + (sCol[dd] == B);
      }
    }
    sCnt[q] = c;
  }
  __syncthreads();

  // Hillis-Steele scan over 441
  sScan[tid] = (tid < 441) ? sCnt[tid] : 0;
  __syncthreads();
  for (int s = 1; s < 512; s <<= 1) {
    int v = (tid >= s) ? sScan[tid - s] : 0;
    __syncthreads();
    sScan[tid] += v;
    __syncthreads();
  }
  if (tid == 0) sOff[0] = 0;
  if (tid < 441) sOff[tid + 1] = sScan[tid];
  __syncthreads();
  for (int q = tid; q < 442; q += 512) ws[WS_ENTOFF + q] = sOff[q];

  // tileMap: rank tiles by entry count DESC (stable) for wave balance
  for (int q = tid; q < 441; q += 512) {
    int c = sCnt[q], r = 0;
    for (int q2 = 0; q2 < 441; ++q2) {
      int c2v = sCnt[q2];
      r += (c2v > c) || (c2v == c && q2 < q);
    }
    ws[WS_TILEMAP + r] = q;
  }

  // fill entries: v = d | dd<<9 | p<<18 | negbit<<22 (negbit=1 -> coef = -c2)
  for (int q = tid; q < 441; q += 512) {
    int A = q / NATOM, B = q % NATOM;
    int o = sOff[q];
    for (int i = 0; i < 20; ++i) {
      int d = sPairs[A * 20 + i];
      int negA = sNeg[A * 20 + i];
      for (int p = 0; p < NPERM; ++p) {
        int dd = sPerm[p * DIMD + d];
        int base = d | (dd << 9) | (p << 18);
        if (sRow[dd] == B) ws[WS_ENTS + (o++)] = base | ((negA ^ 1) << 22);
        if (sCol[dd] == B) ws[WS_ENTS + (o++)] = base | (negA << 22);
      }
    }
  }
}

// ---------------- main kernel: one block per (n, j-column) ----------------
__global__ __launch_bounds__(256, 8) void gdml_main(
    const float* __restrict__ R_desc, const float* __restrict__ R_d_desc,
    const int* __restrict__ j_idxs, const int* __restrict__ ws,
    float* __restrict__ out) {
  const int* perm    = ws + WS_PERM;
  const int* gtab    = ws + WS_GTAB;
  const int* entOff  = ws + WS_ENTOFF;
  const int* ents    = ws + WS_ENTS;
  const int* tileMap = ws + WS_TILEMAP;

  const int bid = blockIdx.x;
  const int jc = bid & 7;
  const int n = bid >> 3;
  const int tid = threadIdx.x;
  const int j = j_idxs[jc];

  __shared__ __align__(16) float4 Rdn4[DIMD];                 // 3,360
  __shared__ __align__(16) float4 Rdj4[DIMD];                 // 3,360
  __shared__ float Rn[DIMD], Rj[DIMD];                        // 1,680
  __shared__ __align__(16) float4 GT4[NPERM][NATOM];          // 4,032
  __shared__ __align__(16) float4 bT4[NPERM][NATOM];          // 4,032
  __shared__ float c1s[NPERM], c2s[NPERM];                    // 96
  __shared__ float partial[252];                              // 1,008
  // ~17.6 KB -> 8 blocks/CU (32 waves)

  // ---- stage inputs ----
  for (int i = tid; i < DIMD; i += 256) {
    Rn[i] = R_desc[(size_t)n * DIMD + i];
    Rj[i] = R_desc[(size_t)j * DIMD + i];
  }
  if (tid < DIMD) {
    const float* gn = R_d_desc + (size_t)n * (DIMD * 3) + 3 * tid;
    const float* gj = R_d_desc + (size_t)j * (DIMD * 3) + 3 * tid;
    Rdn4[tid] = make_float4(gn[0], gn[1], gn[2], 0.f);
    Rdj4[tid] = make_float4(gj[0], gj[1], gj[2], 0.f);
  }
  __syncthreads();

  // ---- norms: diff computed inline (no diffS buffer) ----
  if (tid < 252) {
    int p = tid / 21, seg = tid % 21;
    const int* pp = &perm[p * DIMD + seg * 10];
    const float* rn = &Rn[seg * 10];
    float s = 0.f;
#pragma unroll
    for (int i = 0; i < 10; ++i) {
      float v = rn[i] - Rj[pp[i]];
      s += v * v;
    }
    partial[tid] = s;
  }
  __syncthreads();
  if (tid < NPERM) {
    float s = 0.f;
#pragma unroll
    for (int i = 0; i < 21; ++i) s += partial[tid * 21 + i];
    float nrm = sqrtf(5.0f) * sqrtf(s);
    float mat52 = expf(-nrm / SIGF) * (5.0f / (3.0f * SIGF * SIGF * SIGF * SIGF));
    c1s[tid] = 5.0f * mat52;
    c2s[tid] = (SIGF * SIGF + SIGF * nrm) * mat52;
  }
  __syncthreads();

  // ---- b/G: thread = (p, at); diff values from Rn/Rj identities ----
  // diff[p][d]  = Rn[d]  - Rj[pd]   (pd = perm[p][d])
  // diff[p][tw] = Rn[tw] - Rj[d]    (tw = invperm[p][d])
  if (tid < NPERM * NATOM) {
    int p = tid / NATOM, at = tid % NATOM;
    const int* gt = &gtab[(p * NATOM + at) * 20];
    float g0 = 0, g1 = 0, g2 = 0, b0 = 0, b1 = 0, b2 = 0;
#pragma unroll
    for (int i = 0; i < 20; ++i) {
      int v = gt[i];
      int d = v & 511, tw = (v >> 9) & 511, pd = (v >> 18) & 511;
      unsigned sg = ((unsigned)(v & (1 << 27))) << 4;  // bit27 -> bit31
      float fd = __uint_as_float(__float_as_uint(Rn[d] - Rj[pd]) ^ sg);
      float ftw = __uint_as_float(__float_as_uint(Rn[tw] - Rj[d]) ^ sg);
      float4 rn = Rdn4[d];
      float4 rj = Rdj4[d];
      g0 += rn.x * fd; g1 += rn.y * fd; g2 += rn.z * fd;
      b0 += rj.x * ftw; b1 += rj.y * ftw; b2 += rj.z * ftw;
    }
    float c1 = c1s[p];
    GT4[p][at] = make_float4(c1 * g0, c1 * g1, c1 * g2, 0.f);
    bT4[p][at] = make_float4(b0, b1, b2, 0.f);
  }
  __syncthreads();

  // ---- final: rank-sorted (A,B) 3x3 tiles ----
  const size_t base = (size_t)n * DIMI * (NCOLS * DIMI) + (size_t)jc * DIMI;
#pragma unroll
  for (int pass = 0; pass < 2; ++pass) {
    int rank = tid + pass * 256;
    if (rank < NATOM * NATOM) {
      int q = tileMap[rank];
      int A = q / NATOM, B = q % NATOM;
      float acc[3][3];
#pragma unroll
      for (int c = 0; c < 3; ++c)
#pragma unroll
        for (int e = 0; e < 3; ++e) acc[c][e] = 0.f;

      // term2: acc += (+/-)c2[p] * Rdn[d,:] (x) Rdj[dd,:]
      int o0 = entOff[q], o1 = entOff[q + 1];
      for (int o = o0; o < o1; ++o) {
        int v = ents[o];
        int d = v & 511, dd = (v >> 9) & 511, p = (v >> 18) & 15;
        unsigned sgn = ((unsigned)(v & (1 << 22))) << 9;  // bit22 -> bit31
        float c2 = __uint_as_float(__float_as_uint(c2s[p]) ^ sgn);
        float4 rn = Rdn4[d];
        float4 rj = Rdj4[dd];
        float w0 = c2 * rj.x, w1 = c2 * rj.y, w2 = c2 * rj.z;
        acc[0][0] += rn.x * w0; acc[0][1] += rn.x * w1; acc[0][2] += rn.x * w2;
        acc[1][0] += rn.y * w0; acc[1][1] += rn.y * w1; acc[1][2] += rn.y * w2;
        acc[2][0] += rn.z * w0; acc[2][1] += rn.z * w1; acc[2][2] += rn.z * w2;
      }

      // term1: acc[cg][cb] += sum_p GT4[p][A][cg] * bT4[p][B][cb]  (2 b128 per p)
#pragma unroll
      for (int p = 0; p < NPERM; ++p) {
        float4 g4 = GT4[p][A];
        float4 b4 = bT4[p][B];
        acc[0][0] += g4.x * b4.x; acc[0][1] += g4.x * b4.y; acc[0][2] += g4.x * b4.z;
        acc[1][0] += g4.y * b4.x; acc[1][1] += g4.y * b4.y; acc[1][2] += g4.y * b4.z;
        acc[2][0] += g4.z * b4.x; acc[2][1] += g4.z * b4.y; acc[2][2] += g4.z * b4.z;
      }

#pragma unroll
      for (int cg = 0; cg < 3; ++cg) {
        float* op = out + base + (size_t)(3 * A + cg) * (NCOLS * DIMI) + 3 * B;
        op[0] = acc[cg][0]; op[1] = acc[cg][1]; op[2] = acc[cg][2];
      }
    }
  }
}

extern "C" void kernel_launch(void* const* d_in, const int* in_sizes, int n_in,
                              void* d_out, int out_size, void* d_ws, size_t ws_size,
                              hipStream_t stream) {
  const float* R_desc = (const float*)d_in[0];
  const float* R_d_desc = (const float*)d_in[1];
  const int* tril = (const int*)d_in[2];
  const int* j_idxs = (const int*)d_in[3];
  float* out = (float*)d_out;
  int* ws = (int*)d_ws;

  hipLaunchKernelGGL(gdml_setup, dim3(1), dim3(512), 0, stream, tril, ws);
  hipLaunchKernelGGL(gdml_main, dim3(NTRAIN * NCOLS), dim3(256), 0, stream,
                     R_desc, R_d_desc, j_idxs, ws, out);
}

// Round 9
// 539.130 us; speedup vs baseline: 1.8209x; 1.8209x over previous
//
#include <hip/hip_runtime.h>
#include <math.h>

#define NTRAIN 2000
#define DIMD 210
#define DIMI 63
#define NPERM 12
#define NCOLS 8
#define NATOM 21
#define SIGF 10.0f

// ws layout (ints):
#define WS_PERM      0        // 2520
#define WS_GTAB      6300     // 5040
#define WS_ENTOFF    11340    // 442
#define WS_ENTS      11782    // 10080
#define WS_TILEMAP   21862    // 441
// total 22303 ints (~89 KB)

// ---------------- setup: fully parallel, LDS-staged (~20us) ----------------
__global__ __launch_bounds__(512) void gdml_setup(const int* __restrict__ tril,
                                                  int* __restrict__ ws) {
  __shared__ int sPerm[NPERM * DIMD];
  __shared__ int sInv[NPERM * DIMD];
  __shared__ int sRow[DIMD], sCol[DIMD];
  __shared__ int sPairs[NATOM * 20], sNeg[NATOM * 20];
  __shared__ int sCnt[441];
  __shared__ int sScan[512];
  __shared__ int sOff[442];

  const int tid = threadIdx.x;

  for (int d = tid; d < DIMD; d += 512) {
    int a = 1;
    while ((a * (a + 1)) / 2 <= d) a++;
    sRow[d] = a;
    sCol[d] = d - (a * (a - 1)) / 2;
  }
  for (int idx = tid; idx < NPERM * DIMD; idx += 512) {
    int p = idx / DIMD, d = idx % DIMD;
    sPerm[idx] = tril[d * NPERM + p] % DIMD;
  }
  __syncthreads();
  for (int idx = tid; idx < NPERM * DIMD; idx += 512) {
    int p = idx / DIMD;
    sInv[p * DIMD + sPerm[idx]] = idx % DIMD;
  }
  if (tid < NATOM) {
    int t = tid, c = 0;
    for (int d = 0; d < DIMD; ++d) {
      if (sRow[d] == t)      { sPairs[t * 20 + c] = d; sNeg[t * 20 + c] = 0; c++; }
      else if (sCol[d] == t) { sPairs[t * 20 + c] = d; sNeg[t * 20 + c] = 1; c++; }
    }
  }
  __syncthreads();

  for (int idx = tid; idx < NPERM * DIMD; idx += 512) ws[WS_PERM + idx] = sPerm[idx];
  // gtab[(p*21+at)*20+i] = d | tw<<9 | pd<<18 | neg<<27
  for (int idx = tid; idx < NPERM * NATOM * 20; idx += 512) {
    int p = idx / (NATOM * 20);
    int r = idx % (NATOM * 20);
    int d = sPairs[r], neg = sNeg[r];
    int tw = sInv[p * DIMD + d];
    int pd = sPerm[p * DIMD + d];
    ws[WS_GTAB + idx] = d | (tw << 9) | (pd << 18) | (neg << 27);
  }

  // CSR counts per (A,B)
  for (int q = tid; q < 441; q += 512) {
    int A = q / NATOM, B = q % NATOM, c = 0;
    for (int i = 0; i < 20; ++i) {
      int d = sPairs[A * 20 + i];
      for (int p = 0; p < NPERM; ++p) {
        int dd = sPerm[p * DIMD + d];
        c += (sRow[dd] == B) + (sCol[dd] == B);
      }
    }
    sCnt[q] = c;
  }
  __syncthreads();

  // Hillis-Steele scan over 441
  sScan[tid] = (tid < 441) ? sCnt[tid] : 0;
  __syncthreads();
  for (int s = 1; s < 512; s <<= 1) {
    int v = (tid >= s) ? sScan[tid - s] : 0;
    __syncthreads();
    sScan[tid] += v;
    __syncthreads();
  }
  if (tid == 0) sOff[0] = 0;
  if (tid < 441) sOff[tid + 1] = sScan[tid];
  __syncthreads();
  for (int q = tid; q < 442; q += 512) ws[WS_ENTOFF + q] = sOff[q];

  // tileMap: rank tiles by entry count DESC (stable) for wave balance
  for (int q = tid; q < 441; q += 512) {
    int c = sCnt[q], r = 0;
    for (int q2 = 0; q2 < 441; ++q2) {
      int c2v = sCnt[q2];
      r += (c2v > c) || (c2v == c && q2 < q);
    }
    ws[WS_TILEMAP + r] = q;
  }

  // fill entries: v = d | dd<<9 | p<<18 | negbit<<22 (negbit=1 -> coef = -c2)
  for (int q = tid; q < 441; q += 512) {
    int A = q / NATOM, B = q % NATOM;
    int o = sOff[q];
    for (int i = 0; i < 20; ++i) {
      int d = sPairs[A * 20 + i];
      int negA = sNeg[A * 20 + i];
      for (int p = 0; p < NPERM; ++p) {
        int dd = sPerm[p * DIMD + d];
        int base = d | (dd << 9) | (p << 18);
        if (sRow[dd] == B) ws[WS_ENTS + (o++)] = base | ((negA ^ 1) << 22);
        if (sCol[dd] == B) ws[WS_ENTS + (o++)] = base | (negA << 22);
      }
    }
  }
}

// ---------------- main kernel: one block per (n, j-column) ----------------
__global__ __launch_bounds__(256, 5) void gdml_main(
    const float* __restrict__ R_desc, const float* __restrict__ R_d_desc,
    const int* __restrict__ j_idxs, const int* __restrict__ ws,
    float* __restrict__ out) {
  const int* perm    = ws + WS_PERM;
  const int* gtab    = ws + WS_GTAB;
  const int* entOff  = ws + WS_ENTOFF;
  const int* ents    = ws + WS_ENTS;
  const int* tileMap = ws + WS_TILEMAP;

  const int bid = blockIdx.x;
  const int jc = bid & 7;
  const int n = bid >> 3;
  const int tid = threadIdx.x;
  const int j = j_idxs[jc];

  __shared__ __align__(16) float4 Rdn4[DIMD];        // 3,360
  __shared__ __align__(16) float4 Rdj4[DIMD];        // 3,360
  __shared__ __align__(16) float4 GT4[NPERM][NATOM]; // 4,032
  __shared__ __align__(16) float4 bT4[NPERM][NATOM]; // 4,032
  __shared__ float c1s[NPERM], c2s[NPERM];           // 96
  // union: {Rn[210], Rj[210], partial[252]} (dead after b/G)  vs  out-tile[63][64]
  __shared__ __align__(16) char uni[DIMI * 64 * 4];  // 16,128
  float* Rn = (float*)uni;
  float* Rj = Rn + DIMD;
  float* partial = Rj + DIMD;
  float (*tile)[64] = (float(*)[64])uni;
  // total ~31.0 KB -> 5 blocks/CU (20 waves)

  // ---- stage inputs ----
  for (int i = tid; i < DIMD; i += 256) {
    Rn[i] = R_desc[(size_t)n * DIMD + i];
    Rj[i] = R_desc[(size_t)j * DIMD + i];
  }
  if (tid < DIMD) {
    const float* gn = R_d_desc + (size_t)n * (DIMD * 3) + 3 * tid;
    const float* gj = R_d_desc + (size_t)j * (DIMD * 3) + 3 * tid;
    Rdn4[tid] = make_float4(gn[0], gn[1], gn[2], 0.f);
    Rdj4[tid] = make_float4(gj[0], gj[1], gj[2], 0.f);
  }
  __syncthreads();

  // ---- norms: diff computed inline ----
  if (tid < 252) {
    int p = tid / 21, seg = tid % 21;
    const int* pp = &perm[p * DIMD + seg * 10];
    const float* rn = &Rn[seg * 10];
    float s = 0.f;
#pragma unroll
    for (int i = 0; i < 10; ++i) {
      float v = rn[i] - Rj[pp[i]];
      s += v * v;
    }
    partial[tid] = s;
  }
  __syncthreads();
  if (tid < NPERM) {
    float s = 0.f;
#pragma unroll
    for (int i = 0; i < 21; ++i) s += partial[tid * 21 + i];
    float nrm = sqrtf(5.0f) * sqrtf(s);
    float mat52 = expf(-nrm / SIGF) * (5.0f / (3.0f * SIGF * SIGF * SIGF * SIGF));
    c1s[tid] = 5.0f * mat52;
    c2s[tid] = (SIGF * SIGF + SIGF * nrm) * mat52;
  }
  __syncthreads();

  // ---- b/G: thread = (p, at); diff values from Rn/Rj identities ----
  if (tid < NPERM * NATOM) {
    int p = tid / NATOM, at = tid % NATOM;
    const int* gt = &gtab[(p * NATOM + at) * 20];
    float g0 = 0, g1 = 0, g2 = 0, b0 = 0, b1 = 0, b2 = 0;
#pragma unroll
    for (int i = 0; i < 20; ++i) {
      int v = gt[i];
      int d = v & 511, tw = (v >> 9) & 511, pd = (v >> 18) & 511;
      unsigned sg = ((unsigned)(v & (1 << 27))) << 4;  // bit27 -> bit31
      float fd = __uint_as_float(__float_as_uint(Rn[d] - Rj[pd]) ^ sg);
      float ftw = __uint_as_float(__float_as_uint(Rn[tw] - Rj[d]) ^ sg);
      float4 rn = Rdn4[d];
      float4 rj = Rdj4[d];
      g0 += rn.x * fd; g1 += rn.y * fd; g2 += rn.z * fd;
      b0 += rj.x * ftw; b1 += rj.y * ftw; b2 += rj.z * ftw;
    }
    float c1 = c1s[p];
    GT4[p][at] = make_float4(c1 * g0, c1 * g1, c1 * g2, 0.f);
    bT4[p][at] = make_float4(b0, b1, b2, 0.f);
  }
  __syncthreads();   // after this barrier Rn/Rj/partial are dead -> tile may alias

  // ---- final: rank-sorted (A,B) 3x3 tiles -> LDS tile (NOT global) ----
#pragma unroll
  for (int pass = 0; pass < 2; ++pass) {
    int rank = tid + pass * 256;
    if (rank < NATOM * NATOM) {
      int q = tileMap[rank];
      int A = q / NATOM, B = q % NATOM;
      float acc[3][3];
#pragma unroll
      for (int c = 0; c < 3; ++c)
#pragma unroll
        for (int e = 0; e < 3; ++e) acc[c][e] = 0.f;

      // term2: acc += (+/-)c2[p] * Rdn[d,:] (x) Rdj[dd,:]
      int o0 = entOff[q], o1 = entOff[q + 1];
      for (int o = o0; o < o1; ++o) {
        int v = ents[o];
        int d = v & 511, dd = (v >> 9) & 511, p = (v >> 18) & 15;
        unsigned sgn = ((unsigned)(v & (1 << 22))) << 9;  // bit22 -> bit31
        float c2 = __uint_as_float(__float_as_uint(c2s[p]) ^ sgn);
        float4 rn = Rdn4[d];
        float4 rj = Rdj4[dd];
        float w0 = c2 * rj.x, w1 = c2 * rj.y, w2 = c2 * rj.z;
        acc[0][0] += rn.x * w0; acc[0][1] += rn.x * w1; acc[0][2] += rn.x * w2;
        acc[1][0] += rn.y * w0; acc[1][1] += rn.y * w1; acc[1][2] += rn.y * w2;
        acc[2][0] += rn.z * w0; acc[2][1] += rn.z * w1; acc[2][2] += rn.z * w2;
      }

      // term1: acc[cg][cb] += sum_p GT4[p][A][cg] * bT4[p][B][cb]
#pragma unroll
      for (int p = 0; p < NPERM; ++p) {
        float4 g4 = GT4[p][A];
        float4 b4 = bT4[p][B];
        acc[0][0] += g4.x * b4.x; acc[0][1] += g4.x * b4.y; acc[0][2] += g4.x * b4.z;
        acc[1][0] += g4.y * b4.x; acc[1][1] += g4.y * b4.y; acc[1][2] += g4.y * b4.z;
        acc[2][0] += g4.z * b4.x; acc[2][1] += g4.z * b4.y; acc[2][2] += g4.z * b4.z;
      }

#pragma unroll
      for (int cg = 0; cg < 3; ++cg) {
        tile[3 * A + cg][3 * B + 0] = acc[cg][0];
        tile[3 * A + cg][3 * B + 1] = acc[cg][1];
        tile[3 * A + cg][3 * B + 2] = acc[cg][2];
      }
    }
  }
  __syncthreads();

  // ---- coalesced dump: row-contiguous 252-B chunks (the R2-R5 clean pattern) ----
  const size_t base = (size_t)n * DIMI * (NCOLS * DIMI) + (size_t)jc * DIMI;
  for (int idx = tid; idx < DIMI * DIMI; idx += 256) {
    int k = idx / DIMI, e = idx % DIMI;
    out[base + (size_t)k * (NCOLS * DIMI) + e] = tile[k][e];
  }
}

extern "C" void kernel_launch(void* const* d_in, const int* in_sizes, int n_in,
                              void* d_out, int out_size, void* d_ws, size_t ws_size,
                              hipStream_t stream) {
  const float* R_desc = (const float*)d_in[0];
  const float* R_d_desc = (const float*)d_in[1];
  const int* tril = (const int*)d_in[2];
  const int* j_idxs = (const int*)d_in[3];
  float* out = (float*)d_out;
  int* ws = (int*)d_ws;

  hipLaunchKernelGGL(gdml_setup, dim3(1), dim3(512), 0, stream, tril, ws);
  hipLaunchKernelGGL(gdml_main, dim3(NTRAIN * NCOLS), dim3(256), 0, stream,
                     R_desc, R_d_desc, j_idxs, ws, out);
}

// Round 10
// 473.869 us; speedup vs baseline: 2.0717x; 1.1377x over previous
//
#include <hip/hip_runtime.h>
#include <hip/hip_fp16.h>
#include <math.h>

#define NTRAIN 2000
#define DIMD 210
#define DIMI 63
#define NPERM 12
#define NCOLS 8
#define NATOM 21
#define SIGF 10.0f

// ws layout (ints):
#define WS_PERM      0        // 2520
#define WS_GTAB      6300     // 5040
#define WS_ENTOFF    11340    // 442
#define WS_ENTS      11782    // 10080
#define WS_TILEMAP   21862    // 441

// ---------------- setup: fully parallel, LDS-staged (identical to R9) ----------------
__global__ __launch_bounds__(512) void gdml_setup(const int* __restrict__ tril,
                                                  int* __restrict__ ws) {
  __shared__ int sPerm[NPERM * DIMD];
  __shared__ int sInv[NPERM * DIMD];
  __shared__ int sRow[DIMD], sCol[DIMD];
  __shared__ int sPairs[NATOM * 20], sNeg[NATOM * 20];
  __shared__ int sCnt[441];
  __shared__ int sScan[512];
  __shared__ int sOff[442];

  const int tid = threadIdx.x;

  for (int d = tid; d < DIMD; d += 512) {
    int a = 1;
    while ((a * (a + 1)) / 2 <= d) a++;
    sRow[d] = a;
    sCol[d] = d - (a * (a - 1)) / 2;
  }
  for (int idx = tid; idx < NPERM * DIMD; idx += 512) {
    int p = idx / DIMD, d = idx % DIMD;
    sPerm[idx] = tril[d * NPERM + p] % DIMD;
  }
  __syncthreads();
  for (int idx = tid; idx < NPERM * DIMD; idx += 512) {
    int p = idx / DIMD;
    sInv[p * DIMD + sPerm[idx]] = idx % DIMD;
  }
  if (tid < NATOM) {
    int t = tid, c = 0;
    for (int d = 0; d < DIMD; ++d) {
      if (sRow[d] == t)      { sPairs[t * 20 + c] = d; sNeg[t * 20 + c] = 0; c++; }
      else if (sCol[d] == t) { sPairs[t * 20 + c] = d; sNeg[t * 20 + c] = 1; c++; }
    }
  }
  __syncthreads();

  for (int idx = tid; idx < NPERM * DIMD; idx += 512) ws[WS_PERM + idx] = sPerm[idx];
  // gtab[(p*21+at)*20+i] = d | tw<<9 | pd<<18 | neg<<27
  for (int idx = tid; idx < NPERM * NATOM * 20; idx += 512) {
    int p = idx / (NATOM * 20);
    int r = idx % (NATOM * 20);
    int d = sPairs[r], neg = sNeg[r];
    int tw = sInv[p * DIMD + d];
    int pd = sPerm[p * DIMD + d];
    ws[WS_GTAB + idx] = d | (tw << 9) | (pd << 18) | (neg << 27);
  }

  // CSR counts per (A,B)
  for (int q = tid; q < 441; q += 512) {
    int A = q / NATOM, B = q % NATOM, c = 0;
    for (int i = 0; i < 20; ++i) {
      int d = sPairs[A * 20 + i];
      for (int p = 0; p < NPERM; ++p) {
        int dd = sPerm[p * DIMD + d];
        c += (sRow[dd] == B) + (sCol[dd] == B);
      }
    }
    sCnt[q] = c;
  }
  __syncthreads();

  // Hillis-Steele scan over 441
  sScan[tid] = (tid < 441) ? sCnt[tid] : 0;
  __syncthreads();
  for (int s = 1; s < 512; s <<= 1) {
    int v = (tid >= s) ? sScan[tid - s] : 0;
    __syncthreads();
    sScan[tid] += v;
    __syncthreads();
  }
  if (tid == 0) sOff[0] = 0;
  if (tid < 441) sOff[tid + 1] = sScan[tid];
  __syncthreads();
  for (int q = tid; q < 442; q += 512) ws[WS_ENTOFF + q] = sOff[q];

  // tileMap: rank tiles by entry count DESC (stable) for wave balance
  for (int q = tid; q < 441; q += 512) {
    int c = sCnt[q], r = 0;
    for (int q2 = 0; q2 < 441; ++q2) {
      int c2v = sCnt[q2];
      r += (c2v > c) || (c2v == c && q2 < q);
    }
    ws[WS_TILEMAP + r] = q;
  }

  // fill entries: v = d | dd<<9 | p<<18 | negbit<<22 (negbit=1 -> coef = -c2)
  for (int q = tid; q < 441; q += 512) {
    int A = q / NATOM, B = q % NATOM;
    int o = sOff[q];
    for (int i = 0; i < 20; ++i) {
      int d = sPairs[A * 20 + i];
      int negA = sNeg[A * 20 + i];
      for (int p = 0; p < NPERM; ++p) {
        int dd = sPerm[p * DIMD + d];
        int base = d | (dd << 9) | (p << 18);
        if (sRow[dd] == B) ws[WS_ENTS + (o++)] = base | ((negA ^ 1) << 22);
        if (sCol[dd] == B) ws[WS_ENTS + (o++)] = base | (negA << 22);
      }
    }
  }
}

// fp16 pack/unpack helpers: uint2 = {h(x) | h(y)<<16, h(z)}
__device__ inline unsigned h16(float f) {
  __half h = __float2half_rn(f);
  return (unsigned)__half_as_ushort(h);
}
__device__ inline float uh(unsigned u) {  // low 16 bits -> float
  return __half2float(__ushort_as_half((unsigned short)(u & 0xFFFFu)));
}

// ---------------- main kernel: one block per (n, j-column) ----------------
__global__ __launch_bounds__(256, 6) void gdml_main(
    const float* __restrict__ R_desc, const float* __restrict__ R_d_desc,
    const int* __restrict__ j_idxs, const int* __restrict__ ws,
    float* __restrict__ out) {
  const int* perm    = ws + WS_PERM;
  const int* gtab    = ws + WS_GTAB;
  const int* entOff  = ws + WS_ENTOFF;
  const int* ents    = ws + WS_ENTS;
  const int* tileMap = ws + WS_TILEMAP;

  const int bid = blockIdx.x;
  const int jc = bid & 7;
  const int n = bid >> 3;
  const int tid = threadIdx.x;
  const int j = j_idxs[jc];

  __shared__ uint2 Rdn2[DIMD];                       // 1,680 (fp16x3 packed)
  __shared__ uint2 Rdj2[DIMD];                       // 1,680
  __shared__ float GT[NPERM][64];                    // 3,072 (p-major)
  __shared__ float bT[NPERM][64];                    // 3,072
  __shared__ float c1s[NPERM], c2s[NPERM];           // 96
  // union: {Rn[210], Rj[210], partial[252]} (dead after b/G)  vs  tile[63*63]
  __shared__ __align__(16) char uni[DIMI * DIMI * 4]; // 15,876
  float* Rn = (float*)uni;
  float* Rj = Rn + DIMD;
  float* partial = Rj + DIMD;
  float* tile = (float*)uni;
  // total ~25.5 KB -> 6 blocks/CU (24 waves)

  // ---- stage inputs ----
  for (int i = tid; i < DIMD; i += 256) {
    Rn[i] = R_desc[(size_t)n * DIMD + i];
    Rj[i] = R_desc[(size_t)j * DIMD + i];
  }
  if (tid < DIMD) {
    const float* gn = R_d_desc + (size_t)n * (DIMD * 3) + 3 * tid;
    const float* gj = R_d_desc + (size_t)j * (DIMD * 3) + 3 * tid;
    Rdn2[tid] = make_uint2(h16(gn[0]) | (h16(gn[1]) << 16), h16(gn[2]));
    Rdj2[tid] = make_uint2(h16(gj[0]) | (h16(gj[1]) << 16), h16(gj[2]));
  }
  __syncthreads();

  // ---- norms: diff computed inline (fp32 Rn/Rj) ----
  if (tid < 252) {
    int p = tid / 21, seg = tid % 21;
    const int* pp = &perm[p * DIMD + seg * 10];
    const float* rn = &Rn[seg * 10];
    float s = 0.f;
#pragma unroll
    for (int i = 0; i < 10; ++i) {
      float v = rn[i] - Rj[pp[i]];
      s += v * v;
    }
    partial[tid] = s;
  }
  __syncthreads();
  if (tid < NPERM) {
    float s = 0.f;
#pragma unroll
    for (int i = 0; i < 21; ++i) s += partial[tid * 21 + i];
    float nrm = sqrtf(5.0f) * sqrtf(s);
    float mat52 = expf(-nrm / SIGF) * (5.0f / (3.0f * SIGF * SIGF * SIGF * SIGF));
    c1s[tid] = 5.0f * mat52;
    c2s[tid] = (SIGF * SIGF + SIGF * nrm) * mat52;
  }
  __syncthreads();

  // ---- b/G: thread = (p, at); diff from Rn/Rj identities; b64 fp16 gathers ----
  if (tid < NPERM * NATOM) {
    int p = tid / NATOM, at = tid % NATOM;
    const int* gt = &gtab[(p * NATOM + at) * 20];
    float g0 = 0, g1 = 0, g2 = 0, b0 = 0, b1 = 0, b2 = 0;
#pragma unroll
    for (int i = 0; i < 20; ++i) {
      int v = gt[i];
      int d = v & 511, tw = (v >> 9) & 511, pd = (v >> 18) & 511;
      unsigned sg = ((unsigned)(v & (1 << 27))) << 4;  // bit27 -> bit31
      float fd = __uint_as_float(__float_as_uint(Rn[d] - Rj[pd]) ^ sg);
      float ftw = __uint_as_float(__float_as_uint(Rn[tw] - Rj[d]) ^ sg);
      uint2 rn = Rdn2[d];
      uint2 rj = Rdj2[d];
      g0 += uh(rn.x) * fd;       g1 += uh(rn.x >> 16) * fd;  g2 += uh(rn.y) * fd;
      b0 += uh(rj.x) * ftw;      b1 += uh(rj.x >> 16) * ftw; b2 += uh(rj.y) * ftw;
    }
    float c1 = c1s[p];
    GT[p][3 * at + 0] = c1 * g0;
    GT[p][3 * at + 1] = c1 * g1;
    GT[p][3 * at + 2] = c1 * g2;
    bT[p][3 * at + 0] = b0;
    bT[p][3 * at + 1] = b1;
    bT[p][3 * at + 2] = b2;
  }
  __syncthreads();   // Rn/Rj/partial dead -> tile may alias

  // ---- term2: single pass, paired ranks (t, 440-t) for balance; write LDS tile ----
  for (int s = 0; s < 2; ++s) {
    int rank;
    if (s == 0) { if (tid > 220) break; rank = tid; }
    else        { if (tid >= 220) break; rank = 440 - tid; }
    int q = tileMap[rank];
    int A = q / NATOM, B = q % NATOM;
    float acc[3][3];
#pragma unroll
    for (int c = 0; c < 3; ++c)
#pragma unroll
      for (int e = 0; e < 3; ++e) acc[c][e] = 0.f;

    int o0 = entOff[q], o1 = entOff[q + 1];
    for (int o = o0; o < o1; ++o) {
      int v = ents[o];
      int d = v & 511, dd = (v >> 9) & 511, p = (v >> 18) & 15;
      unsigned sgn = ((unsigned)(v & (1 << 22))) << 9;  // bit22 -> bit31
      float c2 = __uint_as_float(__float_as_uint(c2s[p]) ^ sgn);
      uint2 rn = Rdn2[d];
      uint2 rj = Rdj2[dd];
      float nx = uh(rn.x), ny = uh(rn.x >> 16), nz = uh(rn.y);
      float w0 = c2 * uh(rj.x), w1 = c2 * uh(rj.x >> 16), w2 = c2 * uh(rj.y);
      acc[0][0] += nx * w0; acc[0][1] += nx * w1; acc[0][2] += nx * w2;
      acc[1][0] += ny * w0; acc[1][1] += ny * w1; acc[1][2] += ny * w2;
      acc[2][0] += nz * w0; acc[2][1] += nz * w1; acc[2][2] += nz * w2;
    }
#pragma unroll
    for (int cg = 0; cg < 3; ++cg) {
      tile[(3 * A + cg) * DIMI + 3 * B + 0] = acc[cg][0];
      tile[(3 * A + cg) * DIMI + 3 * B + 1] = acc[cg][1];
      tile[(3 * A + cg) * DIMI + 3 * B + 2] = acc[cg][2];
    }
  }
  __syncthreads();

  // ---- dump + term1: out[k,e] = tile[k*63+e] + sum_p GT[p][k]*bT[p][e] ----
  const size_t base = (size_t)n * DIMI * (NCOLS * DIMI) + (size_t)jc * DIMI;
  for (int idx = tid; idx < DIMI * DIMI; idx += 256) {
    int k = idx / DIMI, e = idx - k * DIMI;
    float a = tile[idx];
#pragma unroll
    for (int p = 0; p < NPERM; ++p) a += GT[p][k] * bT[p][e];
    out[base + (size_t)k * (NCOLS * DIMI) + e] = a;
  }
}

extern "C" void kernel_launch(void* const* d_in, const int* in_sizes, int n_in,
                              void* d_out, int out_size, void* d_ws, size_t ws_size,
                              hipStream_t stream) {
  const float* R_desc = (const float*)d_in[0];
  const float* R_d_desc = (const float*)d_in[1];
  const int* tril = (const int*)d_in[2];
  const int* j_idxs = (const int*)d_in[3];
  float* out = (float*)d_out;
  int* ws = (int*)d_ws;

  hipLaunchKernelGGL(gdml_setup, dim3(1), dim3(512), 0, stream, tril, ws);
  hipLaunchKernelGGL(gdml_main, dim3(NTRAIN * NCOLS), dim3(256), 0, stream,
                     R_desc, R_d_desc, j_idxs, ws, out);
}

// Round 11
// 440.325 us; speedup vs baseline: 2.2295x; 1.0762x over previous
//
#include <hip/hip_runtime.h>
#include <hip/hip_fp16.h>
#include <math.h>

#define NTRAIN 2000
#define DIMD 210
#define DIMI 63
#define NPERM 12
#define NCOLS 8
#define NATOM 21
#define SIGF 10.0f

// ws layout (ints):
#define WS_PERM      0        // 2520
#define WS_GTAB      6300     // 5040
#define WS_ENTOFF    11340    // 442
#define WS_ENTS      11782    // 10080
#define WS_TILEMAP   21862    // 441

// ---------------- setup: fully parallel, LDS-staged ----------------
__global__ __launch_bounds__(512) void gdml_setup(const int* __restrict__ tril,
                                                  int* __restrict__ ws) {
  __shared__ int sPerm[NPERM * DIMD];
  __shared__ int sInv[NPERM * DIMD];
  __shared__ int sRow[DIMD], sCol[DIMD];
  __shared__ int sPairs[NATOM * 20], sNeg[NATOM * 20];
  __shared__ int sCnt[441];
  __shared__ int sScan[512];
  __shared__ int sOff[442];

  const int tid = threadIdx.x;

  for (int d = tid; d < DIMD; d += 512) {
    int a = 1;
    while ((a * (a + 1)) / 2 <= d) a++;
    sRow[d] = a;
    sCol[d] = d - (a * (a - 1)) / 2;
  }
  for (int idx = tid; idx < NPERM * DIMD; idx += 512) {
    int p = idx / DIMD, d = idx % DIMD;
    sPerm[idx] = tril[d * NPERM + p] % DIMD;
  }
  __syncthreads();
  for (int idx = tid; idx < NPERM * DIMD; idx += 512) {
    int p = idx / DIMD;
    sInv[p * DIMD + sPerm[idx]] = idx % DIMD;
  }
  if (tid < NATOM) {
    int t = tid, c = 0;
    for (int d = 0; d < DIMD; ++d) {
      if (sRow[d] == t)      { sPairs[t * 20 + c] = d; sNeg[t * 20 + c] = 0; c++; }
      else if (sCol[d] == t) { sPairs[t * 20 + c] = d; sNeg[t * 20 + c] = 1; c++; }
    }
  }
  __syncthreads();

  for (int idx = tid; idx < NPERM * DIMD; idx += 512) ws[WS_PERM + idx] = sPerm[idx];
  // gtab[(p*21+at)*20+i] = d | tw<<9 | pd<<18 | neg<<27
  for (int idx = tid; idx < NPERM * NATOM * 20; idx += 512) {
    int p = idx / (NATOM * 20);
    int r = idx % (NATOM * 20);
    int d = sPairs[r], neg = sNeg[r];
    int tw = sInv[p * DIMD + d];
    int pd = sPerm[p * DIMD + d];
    ws[WS_GTAB + idx] = d | (tw << 9) | (pd << 18) | (neg << 27);
  }

  // CSR counts per (A,B)
  for (int q = tid; q < 441; q += 512) {
    int A = q / NATOM, B = q % NATOM, c = 0;
    for (int i = 0; i < 20; ++i) {
      int d = sPairs[A * 20 + i];
      for (int p = 0; p < NPERM; ++p) {
        int dd = sPerm[p * DIMD + d];
        c += (sRow[dd] == B) + (sCol[dd] == B);
      }
    }
    sCnt[q] = c;
  }
  __syncthreads();

  // Hillis-Steele scan over 441
  sScan[tid] = (tid < 441) ? sCnt[tid] : 0;
  __syncthreads();
  for (int s = 1; s < 512; s <<= 1) {
    int v = (tid >= s) ? sScan[tid - s] : 0;
    __syncthreads();
    sScan[tid] += v;
    __syncthreads();
  }
  if (tid == 0) sOff[0] = 0;
  if (tid < 441) sOff[tid + 1] = sScan[tid];
  __syncthreads();
  for (int q = tid; q < 442; q += 512) ws[WS_ENTOFF + q] = sOff[q];

  // tileMap: rank tiles by entry count DESC (stable) for wave balance
  for (int q = tid; q < 441; q += 512) {
    int c = sCnt[q], r = 0;
    for (int q2 = 0; q2 < 441; ++q2) {
      int c2v = sCnt[q2];
      r += (c2v > c) || (c2v == c && q2 < q);
    }
    ws[WS_TILEMAP + r] = q;
  }

  // fill entries: v = d | dd<<9 | p<<18 | negbit<<22 (negbit=1 -> coef = -c2)
  for (int q = tid; q < 441; q += 512) {
    int A = q / NATOM, B = q % NATOM;
    int o = sOff[q];
    for (int i = 0; i < 20; ++i) {
      int d = sPairs[A * 20 + i];
      int negA = sNeg[A * 20 + i];
      for (int p = 0; p < NPERM; ++p) {
        int dd = sPerm[p * DIMD + d];
        int base = d | (dd << 9) | (p << 18);
        if (sRow[dd] == B) ws[WS_ENTS + (o++)] = base | ((negA ^ 1) << 22);
        if (sCol[dd] == B) ws[WS_ENTS + (o++)] = base | (negA << 22);
      }
    }
  }
}

// fp16 pack/unpack helpers: uint2 = {h(x) | h(y)<<16, h(z)}
__device__ inline unsigned h16(float f) {
  __half h = __float2half_rn(f);
  return (unsigned)__half_as_ushort(h);
}
__device__ inline float uh(unsigned u) {  // low 16 bits -> float
  return __half2float(__ushort_as_half((unsigned short)(u & 0xFFFFu)));
}

// ---------------- main kernel: one block per (n, j-column) ----------------
__global__ __launch_bounds__(256, 6) void gdml_main(
    const float* __restrict__ R_desc, const float* __restrict__ R_d_desc,
    const int* __restrict__ j_idxs, const int* __restrict__ ws,
    float* __restrict__ out) {
  const int* perm    = ws + WS_PERM;
  const int* gtab    = ws + WS_GTAB;
  const int* entOff  = ws + WS_ENTOFF;
  const int* ents    = ws + WS_ENTS;
  const int* tileMap = ws + WS_TILEMAP;

  const int bid = blockIdx.x;
  const int jc = bid & 7;
  const int n = bid >> 3;
  const int tid = threadIdx.x;
  const int j = j_idxs[jc];

  __shared__ uint2 Rdn2[DIMD];                        // 1,680 (fp16x3 packed)
  __shared__ uint2 Rdj2[DIMD];                        // 1,680
  __shared__ __align__(16) float GT[NPERM][64];       // 3,072 (p-major)
  __shared__ __align__(16) float bT[NPERM][64];       // 3,072
  __shared__ float c1s[NPERM], c2s[NPERM];            // 96
  // union: {Rn[210], Rj[210], partial[252]} (dead after b/G)  vs  tile[63][64]
  __shared__ __align__(16) char uni[DIMI * 64 * 4];   // 16,128
  float* Rn = (float*)uni;
  float* Rj = Rn + DIMD;
  float* partial = Rj + DIMD;
  float* tile = (float*)uni;                          // row stride 64
  // total ~25.7 KB -> 6 blocks/CU (24 waves)

  // ---- stage inputs ----
  for (int i = tid; i < DIMD; i += 256) {
    Rn[i] = R_desc[(size_t)n * DIMD + i];
    Rj[i] = R_desc[(size_t)j * DIMD + i];
  }
  if (tid < DIMD) {
    const float* gn = R_d_desc + (size_t)n * (DIMD * 3) + 3 * tid;
    const float* gj = R_d_desc + (size_t)j * (DIMD * 3) + 3 * tid;
    Rdn2[tid] = make_uint2(h16(gn[0]) | (h16(gn[1]) << 16), h16(gn[2]));
    Rdj2[tid] = make_uint2(h16(gj[0]) | (h16(gj[1]) << 16), h16(gj[2]));
  }
  __syncthreads();

  // ---- norms: diff computed inline (fp32 Rn/Rj) ----
  if (tid < 252) {
    int p = tid / 21, seg = tid % 21;
    const int* pp = &perm[p * DIMD + seg * 10];
    const float* rn = &Rn[seg * 10];
    float s = 0.f;
#pragma unroll
    for (int i = 0; i < 10; ++i) {
      float v = rn[i] - Rj[pp[i]];
      s += v * v;
    }
    partial[tid] = s;
  }
  __syncthreads();
  if (tid < NPERM) {
    float s = 0.f;
#pragma unroll
    for (int i = 0; i < 21; ++i) s += partial[tid * 21 + i];
    float nrm = sqrtf(5.0f) * sqrtf(s);
    float mat52 = expf(-nrm / SIGF) * (5.0f / (3.0f * SIGF * SIGF * SIGF * SIGF));
    c1s[tid] = 5.0f * mat52;
    c2s[tid] = (SIGF * SIGF + SIGF * nrm) * mat52;
  }
  __syncthreads();

  // ---- b/G: thread = (p, at); diff from Rn/Rj identities; b64 fp16 gathers ----
  if (tid < NPERM * NATOM) {
    int p = tid / NATOM, at = tid % NATOM;
    const int* gt = &gtab[(p * NATOM + at) * 20];
    float g0 = 0, g1 = 0, g2 = 0, b0 = 0, b1 = 0, b2 = 0;
#pragma unroll
    for (int i = 0; i < 20; ++i) {
      int v = gt[i];
      int d = v & 511, tw = (v >> 9) & 511, pd = (v >> 18) & 511;
      unsigned sg = ((unsigned)(v & (1 << 27))) << 4;  // bit27 -> bit31
      float fd = __uint_as_float(__float_as_uint(Rn[d] - Rj[pd]) ^ sg);
      float ftw = __uint_as_float(__float_as_uint(Rn[tw] - Rj[d]) ^ sg);
      uint2 rn = Rdn2[d];
      uint2 rj = Rdj2[d];
      g0 += uh(rn.x) * fd;       g1 += uh(rn.x >> 16) * fd;  g2 += uh(rn.y) * fd;
      b0 += uh(rj.x) * ftw;      b1 += uh(rj.x >> 16) * ftw; b2 += uh(rj.y) * ftw;
    }
    float c1 = c1s[p];
    GT[p][3 * at + 0] = c1 * g0;
    GT[p][3 * at + 1] = c1 * g1;
    GT[p][3 * at + 2] = c1 * g2;
    bT[p][3 * at + 0] = b0;
    bT[p][3 * at + 1] = b1;
    bT[p][3 * at + 2] = b2;
  }
  __syncthreads();   // Rn/Rj/partial dead -> tile may alias

  // ---- term2: single pass, paired ranks (t, 440-t); write LDS tile (stride 64) ----
  for (int s = 0; s < 2; ++s) {
    int rank;
    if (s == 0) { if (tid > 220) break; rank = tid; }
    else        { if (tid >= 220) break; rank = 440 - tid; }
    int q = tileMap[rank];
    int A = q / NATOM, B = q % NATOM;
    float acc[3][3];
#pragma unroll
    for (int c = 0; c < 3; ++c)
#pragma unroll
      for (int e = 0; e < 3; ++e) acc[c][e] = 0.f;

    int o0 = entOff[q], o1 = entOff[q + 1];
    for (int o = o0; o < o1; ++o) {
      int v = ents[o];
      int d = v & 511, dd = (v >> 9) & 511, p = (v >> 18) & 15;
      unsigned sgn = ((unsigned)(v & (1 << 22))) << 9;  // bit22 -> bit31
      float c2 = __uint_as_float(__float_as_uint(c2s[p]) ^ sgn);
      uint2 rn = Rdn2[d];
      uint2 rj = Rdj2[dd];
      float nx = uh(rn.x), ny = uh(rn.x >> 16), nz = uh(rn.y);
      float w0 = c2 * uh(rj.x), w1 = c2 * uh(rj.x >> 16), w2 = c2 * uh(rj.y);
      acc[0][0] += nx * w0; acc[0][1] += nx * w1; acc[0][2] += nx * w2;
      acc[1][0] += ny * w0; acc[1][1] += ny * w1; acc[1][2] += ny * w2;
      acc[2][0] += nz * w0; acc[2][1] += nz * w1; acc[2][2] += nz * w2;
    }
#pragma unroll
    for (int cg = 0; cg < 3; ++cg) {
      tile[(3 * A + cg) * 64 + 3 * B + 0] = acc[cg][0];
      tile[(3 * A + cg) * 64 + 3 * B + 1] = acc[cg][1];
      tile[(3 * A + cg) * 64 + 3 * B + 2] = acc[cg][2];
    }
  }
  __syncthreads();

  // ---- dump + term1, 16-wide register tile: thread = (k, ec); e = ec*16 .. +15 ----
  // out[k,e] = tile[k][e] + sum_p GT[p][k] * bT[p][e]
  const size_t base = (size_t)n * DIMI * (NCOLS * DIMI) + (size_t)jc * DIMI;
  if (tid < 252) {
    int k = tid >> 2, ec = tid & 3;
    int e0 = ec * 16;
    float acc[16];
    {
      const float4* tp = (const float4*)&tile[k * 64 + e0];
      float4 t0 = tp[0], t1 = tp[1], t2 = tp[2], t3 = tp[3];
      acc[0] = t0.x;  acc[1] = t0.y;  acc[2] = t0.z;  acc[3] = t0.w;
      acc[4] = t1.x;  acc[5] = t1.y;  acc[6] = t1.z;  acc[7] = t1.w;
      acc[8] = t2.x;  acc[9] = t2.y;  acc[10] = t2.z; acc[11] = t2.w;
      acc[12] = t3.x; acc[13] = t3.y; acc[14] = t3.z; acc[15] = t3.w;
    }
#pragma unroll
    for (int p = 0; p < NPERM; ++p) {
      float g = GT[p][k];
      const float4* bp = (const float4*)&bT[p][e0];
      float4 b0 = bp[0], b1 = bp[1], b2 = bp[2], b3 = bp[3];
      acc[0] += g * b0.x;  acc[1] += g * b0.y;  acc[2] += g * b0.z;  acc[3] += g * b0.w;
      acc[4] += g * b1.x;  acc[5] += g * b1.y;  acc[6] += g * b1.z;  acc[7] += g * b1.w;
      acc[8] += g * b2.x;  acc[9] += g * b2.y;  acc[10] += g * b2.z; acc[11] += g * b2.w;
      acc[12] += g * b3.x; acc[13] += g * b3.y; acc[14] += g * b3.z; acc[15] += g * b3.w;
    }
    float* op = out + base + (size_t)k * (NCOLS * DIMI) + e0;
    const int lim = DIMI - e0;  // 16,16,16,15
#pragma unroll
    for (int i = 0; i < 16; ++i)
      if (i < lim) op[i] = acc[i];
  }
}

extern "C" void kernel_launch(void* const* d_in, const int* in_sizes, int n_in,
                              void* d_out, int out_size, void* d_ws, size_t ws_size,
                              hipStream_t stream) {
  const float* R_desc = (const float*)d_in[0];
  const float* R_d_desc = (const float*)d_in[1];
  const int* tril = (const int*)d_in[2];
  const int* j_idxs = (const int*)d_in[3];
  float* out = (float*)d_out;
  int* ws = (int*)d_ws;

  hipLaunchKernelGGL(gdml_setup, dim3(1), dim3(512), 0, stream, tril, ws);
  hipLaunchKernelGGL(gdml_main, dim3(NTRAIN * NCOLS), dim3(256), 0, stream,
                     R_desc, R_d_desc, j_idxs, ws, out);
}